// Round 5
// baseline (7522.953 us; speedup 1.0000x reference)
//
#include <hip/hip_runtime.h>

#define Bdim 128
#define Tdim 256
#define Hdim 512
#define INdim 300
#define KXdim 320
#define NC 45
#define NTHR 256
#define NH 512    // threads per pipe block (8 waves)
#define FPAD 16   // ints per flag (64B cache line padding)

typedef _Float16 h16;
typedef __attribute__((ext_vector_type(8))) _Float16 half8;
typedef __attribute__((ext_vector_type(4))) float float4v;
typedef unsigned long long u64;

// ---- coherence-point access helpers: agent-scope atomics ----
__device__ __forceinline__ int ld_flag(const int* p) {
    return __hip_atomic_load((int*)p, __ATOMIC_RELAXED, __HIP_MEMORY_SCOPE_AGENT);
}
__device__ __forceinline__ void st_flag_rel(int* p, int v) {
    __hip_atomic_store(p, v, __ATOMIC_RELEASE, __HIP_MEMORY_SCOPE_AGENT);
}
__device__ __forceinline__ half8 ld16c(const h16* p) {
    union { u64 u[2]; half8 h; } r;
    const u64* q = (const u64*)p;
    r.u[0] = __hip_atomic_load((u64*)(q + 0), __ATOMIC_RELAXED, __HIP_MEMORY_SCOPE_AGENT);
    r.u[1] = __hip_atomic_load((u64*)(q + 1), __ATOMIC_RELAXED, __HIP_MEMORY_SCOPE_AGENT);
    return r.h;
}
__device__ __forceinline__ float4v ld16cf(const float* p) {
    union { u64 u[2]; float4v f; } r;
    const u64* q = (const u64*)p;
    r.u[0] = __hip_atomic_load((u64*)(q + 0), __ATOMIC_RELAXED, __HIP_MEMORY_SCOPE_AGENT);
    r.u[1] = __hip_atomic_load((u64*)(q + 1), __ATOMIC_RELAXED, __HIP_MEMORY_SCOPE_AGENT);
    return r.f;
}
__device__ __forceinline__ void st16cf(float* p, float4v v) {
    union { float4v f; u64 u[2]; } w; w.f = v;
    u64* q = (u64*)p;
    __hip_atomic_store(q + 0, w.u[0], __ATOMIC_RELAXED, __HIP_MEMORY_SCOPE_AGENT);
    __hip_atomic_store(q + 1, w.u[1], __ATOMIC_RELAXED, __HIP_MEMORY_SCOPE_AGENT);
}
__device__ __forceinline__ void st8c(h16* p, const uint* u) {
    uint* q = (uint*)p;
    __hip_atomic_store(q + 0, u[0], __ATOMIC_RELAXED, __HIP_MEMORY_SCOPE_AGENT);
    __hip_atomic_store(q + 1, u[1], __ATOMIC_RELAXED, __HIP_MEMORY_SCOPE_AGENT);
    __hip_atomic_store(q + 2, u[2], __ATOMIC_RELAXED, __HIP_MEMORY_SCOPE_AGENT);
    __hip_atomic_store(q + 3, u[3], __ATOMIC_RELAXED, __HIP_MEMORY_SCOPE_AGENT);
}

// ---------------- prep1: W0 = Wemb @ Wx0 (fp32), cb fused biases ----------------
__global__ __launch_bounds__(NTHR) void prep1_kernel(
    const float* Wemb, const float* bemb,
    const float* Wx_l2r, const float* bx_l2r, const float* bh_l2r,
    const float* Wx_r2l, const float* bx_r2l, const float* bh_r2l,
    float* W0, float* cb)
{
    int gid = blockIdx.x * NTHR + threadIdx.x;
    const int nW0 = 2 * KXdim * Hdim;
    if (gid < nW0) {
        int dir = gid / (KXdim * Hdim);
        int rem = gid % (KXdim * Hdim);
        int i = rem / Hdim, h = rem % Hdim;
        const float* Wx = dir ? Wx_r2l : Wx_l2r;
        float s = 0.f;
        if (i < INdim) {
            for (int k = 0; k < Hdim; ++k)
                s += Wemb[i * Hdim + k] * Wx[k * Hdim + h];
        }
        W0[gid] = s;
    } else {
        int idx = gid - nW0;
        if (idx < 2 * 3 * Hdim) {
            int dir = idx / (3 * Hdim);
            int l = (idx / Hdim) % 3;
            int h = idx % Hdim;
            const float* Wx = dir ? Wx_r2l : Wx_l2r;
            const float* bx = dir ? bx_r2l : bx_l2r;
            const float* bh = dir ? bh_r2l : bh_l2r;
            float s = bx[l * Hdim + h] + bh[l * Hdim + h];
            if (l == 0) {
                for (int k = 0; k < Hdim; ++k)
                    s += bemb[k] * Wx[k * Hdim + h];
            }
            cb[idx] = s;
        }
    }
}

// ---------------- pack_W: fp16 B-frag layout [u][cs16][ks32][nt2][lane64][j8] ----
__global__ __launch_bounds__(NTHR) void pack_W_kernel(
    const float* W0,
    const float* Wx_l2r, const float* Wh_l2r,
    const float* Wx_r2l, const float* Wh_r2l,
    h16* Wfrag)
{
    int e = blockIdx.x * NTHR + threadIdx.x;
    if (e >= 6 * 16 * 32 * 2 * 64 * 8) return;
    int j    = e & 7;
    int lane = (e >> 3) & 63;
    int nt   = (e >> 9) & 1;
    int ks   = (e >> 10) & 31;
    int cs   = (e >> 15) & 15;
    int u    = e >> 19;
    int dir = u / 3, l = u % 3;
    int n  = cs * 32 + nt * 16 + (lane & 15);
    int kk = ks * 32 + ((lane >> 4) * 8) + j;
    float v;
    if (kk < 512) {
        if (l == 0) {
            v = (kk < KXdim) ? W0[(dir * KXdim + kk) * Hdim + n] : 0.f;
        } else {
            const float* Wx = dir ? Wx_r2l : Wx_l2r;
            v = Wx[(l * Hdim + kk) * Hdim + n];
        }
    } else {
        const float* Wh = dir ? Wh_r2l : Wh_l2r;
        v = Wh[(l * Hdim + (kk - 512)) * Hdim + n];
    }
    Wfrag[e] = (h16)v;
}

// ---------------- pack_W0f: fp16 B-frags of W0 for zx0 kernel --------------------
__global__ __launch_bounds__(NTHR) void pack_W0f_kernel(const float* W0, h16* W0f)
{
    int e = blockIdx.x * NTHR + threadIdx.x;
    if (e >= 2 * 32 * 10 * 64 * 8) return;
    int j    = e & 7;
    int lane = (e >> 3) & 63;
    int rest = e >> 9;
    int ks   = rest % 10;
    rest /= 10;
    int nt   = rest & 31;
    int dir  = rest >> 5;
    int k = ks * 32 + ((lane >> 4) * 8) + j;
    int n = nt * 16 + (lane & 15);
    W0f[e] = (h16)W0[(dir * KXdim + k) * Hdim + n];
}

// ---------------- zx0: zx0f[dir][t][nt32][mt8][lane64][reg4] fp16 ----------------
__global__ __launch_bounds__(NTHR) void zx0_kernel(
    const float* __restrict__ x0, const float* __restrict__ x1,
    const h16* __restrict__ W0f, const float* __restrict__ cb,
    h16* __restrict__ zx0f)
{
    int bx = blockIdx.x;
    int t = bx & 255, mh = (bx >> 8) & 1, dir = bx >> 9;
    const int tid = threadIdx.x;
    __shared__ h16 xl[64 * 328];
    const float* xs = dir ? x1 : x0;
    for (int i = tid; i < 64 * 328; i += NTHR) {
        int r = i / 328, k = i - r * 328;
        int b = mh * 64 + r;
        float v = (k < INdim) ? xs[(b * Tdim + t) * INdim + k] : 0.f;
        xl[i] = (h16)v;
    }
    __syncthreads();
    int wave = tid >> 6, lane = tid & 63;
    int r15 = lane & 15, q = lane >> 4;
    for (int nt = 0; nt < 32; ++nt) {
        float4v acc = {0.f, 0.f, 0.f, 0.f};
        #pragma unroll
        for (int ks = 0; ks < 10; ++ks) {
            half8 af = *(const half8*)&xl[(wave * 16 + r15) * 328 + ks * 32 + q * 8];
            half8 bf = *(const half8*)&W0f[(((dir * 32 + nt) * 10 + ks) * 64 + lane) * 8];
            acc = __builtin_amdgcn_mfma_f32_16x16x32_f16(af, bf, acc, 0, 0, 0);
        }
        int col = nt * 16 + r15;
        float cbv = cb[(dir * 3 + 0) * Hdim + col];
        union { h16 h[4]; uint2 u2; } o;
        #pragma unroll
        for (int r = 0; r < 4; ++r) o.h[r] = (h16)(acc[r] + cbv);
        h16* dst = zx0f + (((( (size_t)dir * Tdim + t) * 32 + nt) * 8 + (mh * 4 + wave)) * 64 + lane) * 4;
        *(uint2*)dst = o.u2;
    }
}

// ---------------- zeroinit: flags ------------------------------------------------
__global__ __launch_bounds__(NTHR) void zeroinit_kernel(int* hdone, int* zxdone)
{
    int gid = blockIdx.x * NTHR + threadIdx.x;
    if (gid < 12 * FPAD) hdone[gid] = 0;
    if (gid < 96 * FPAD) zxdone[gid] = 0;
}

// ---------------- main persistent pipeline kernel --------------------------------
// H blocks (12 = 6 units x 2 mtblk, 512 thr): own 64 rows x full N=512. The
// recurrence z(t-1)->z(t) is block-LOCAL: z stays in f32 C-frags; LN stats via
// intra-block LDS reduce; tanh once/elem; h -> LDS transpose -> Wh GEMM (B
// streamed from L2). Publishes post-tanh h frags (for upper X) / h2 (l==2).
// X blocks (64 = 4 units x 16, 512 thr): pure GEMM h_lower(t) @ Wx + cb -> zx.
struct PipeArgs {
    const h16* Wfrag;    // [6][cs16][ks32][nt2][64][8]
    const h16* zx0f;     // [2][T][nt32][mt8][64][4] fp16
    const float* cb;     // [2][3][H]
    const float* lng;    // [3][H]
    const float* lnb;    // [3][H]
    h16* hbuf;           // [6][slot4][ks16][mt8][64][8]  post-tanh h, A-frag layout
    float* zxbuf;        // [6][slot4][nt32][mt8][64][4]  f32 C-frags (x-part + cb)
    h16* h2;             // [2][T][B][H]
    int* hdone;          // [12] * FPAD   (u*2+mtblk)
    int* zxdone;         // [96] * FPAD   (xu*16 + mtblk*8 + cx)
};

struct HS {
    h16 h[64 * 536];        // 68.6 KB, row pad 536 (16B-aligned rows, 2-way banks)
    float red_s[8][64];
    float red_q[8][64];
    float mr[64][2];        // rstd, -m*rstd
    float g2b2[512][2];     // 2g, 2b
};
struct XS { h16 wx[16 * 4 * 64 * 8]; };  // 64 KB Wx frags
union SMem { HS H; XS X; };

__global__ __launch_bounds__(NH, 2) void rnn_pipe(PipeArgs a)
{
    __shared__ SMem sm;
    const int blk = blockIdx.x, tid = threadIdx.x;
    const int w4 = tid >> 6, lane = tid & 63;
    const int r15 = lane & 15, quad = lane >> 4;

    if (blk < 12) {
        // ================= H role =================
        const int u = blk >> 1, mtblk = blk & 1;
        const int dir = u / 3, l = u % 3;

        for (int i = tid; i < Hdim; i += NH) {
            sm.H.g2b2[i][0] = 2.0f * a.lng[l * Hdim + i];
            sm.H.g2b2[i][1] = 2.0f * a.lnb[l * Hdim + i];
        }
        __syncthreads();

        const int loff = lane * 8;
        const h16* wbase[4];
        #pragma unroll
        for (int n = 0; n < 4; ++n) {
            int ntg = w4 * 4 + n;
            wbase[n] = a.Wfrag + (((size_t)(u * 16 + (ntg >> 1)) * 32 + 16) * 2 + (ntg & 1)) * 512;
        }

        float4v acc[4][4];

        // stats + tanh + LDS transpose + publish(h(tm1)); acc holds z(tm1) (f32)
        auto convert = [&](int tm1) {
            float s16[4][4], q16[4][4];
            #pragma unroll
            for (int mt = 0; mt < 4; ++mt)
                #pragma unroll
                for (int r = 0; r < 4; ++r) { s16[mt][r] = 0.f; q16[mt][r] = 0.f; }
            #pragma unroll
            for (int mt = 0; mt < 4; ++mt)
                #pragma unroll
                for (int n = 0; n < 4; ++n)
                    #pragma unroll
                    for (int r = 0; r < 4; ++r) {
                        float v = acc[mt][n][r];
                        s16[mt][r] += v;
                        q16[mt][r] = __builtin_fmaf(v, v, q16[mt][r]);
                    }
            #pragma unroll
            for (int mt = 0; mt < 4; ++mt)
                #pragma unroll
                for (int r = 0; r < 4; ++r) {
                    float s = s16[mt][r], q = q16[mt][r];
                    s += __shfl_xor(s, 1); q += __shfl_xor(q, 1);
                    s += __shfl_xor(s, 2); q += __shfl_xor(q, 2);
                    s += __shfl_xor(s, 4); q += __shfl_xor(q, 4);
                    s += __shfl_xor(s, 8); q += __shfl_xor(q, 8);
                    s16[mt][r] = s; q16[mt][r] = q;
                }
            if (r15 == 0) {
                #pragma unroll
                for (int mt = 0; mt < 4; ++mt)
                    #pragma unroll
                    for (int r = 0; r < 4; ++r) {
                        int row = mt * 16 + quad * 4 + r;
                        sm.H.red_s[w4][row] = s16[mt][r];
                        sm.H.red_q[w4][row] = q16[mt][r];
                    }
            }
            __syncthreads();
            if (tid < 64) {
                float ss = 0.f, qq = 0.f;
                #pragma unroll
                for (int ww = 0; ww < 8; ++ww) { ss += sm.H.red_s[ww][tid]; qq += sm.H.red_q[ww][tid]; }
                float m = ss * (1.0f / Hdim);
                float var = qq * (1.0f / Hdim) - m * m;
                float rstd = rsqrtf(var + 1e-5f);
                sm.H.mr[tid][0] = rstd;
                sm.H.mr[tid][1] = -m * rstd;
            }
            __syncthreads();
            float rA[4][4], rC[4][4];
            #pragma unroll
            for (int mt = 0; mt < 4; ++mt)
                #pragma unroll
                for (int r = 0; r < 4; ++r) {
                    int row = mt * 16 + quad * 4 + r;
                    rA[mt][r] = sm.H.mr[row][0];
                    rC[mt][r] = sm.H.mr[row][1];
                }
            float gg[4], bg[4];
            #pragma unroll
            for (int n = 0; n < 4; ++n) {
                int col = (w4 * 4 + n) * 16 + r15;
                gg[n] = sm.H.g2b2[col][0];
                bg[n] = sm.H.g2b2[col][1];
            }
            #pragma unroll
            for (int mt = 0; mt < 4; ++mt)
                #pragma unroll
                for (int n = 0; n < 4; ++n)
                    #pragma unroll
                    for (int r = 0; r < 4; ++r) {
                        float x2 = __builtin_fmaf(
                            __builtin_fmaf(acc[mt][n][r], rA[mt][r], rC[mt][r]), gg[n], bg[n]);
                        float E = __expf(x2);
                        sm.H.h[(mt * 16 + quad * 4 + r) * 536 + (w4 * 4 + n) * 16 + r15] =
                            (h16)(1.0f - __fdividef(2.0f, E + 1.0f));
                    }
            __syncthreads();
            if (l < 2) {
                h16* dstb = a.hbuf + (size_t)(u * 4 + (tm1 & 3)) * 65536;
                #pragma unroll
                for (int i = 0; i < 8; ++i) {
                    int f = tid + i * NH;
                    int ks = f >> 8, mt4 = (f >> 6) & 3, ln = f & 63;
                    union { half8 v; uint uu[4]; } o;
                    o.v = *(const half8*)&sm.H.h[(mt4 * 16 + (ln & 15)) * 536 + ks * 32 + (ln >> 4) * 8];
                    st8c(dstb + ((size_t)((ks * 8 + (mtblk * 4 + mt4)) * 64) + ln) * 8, o.uu);
                }
            } else {
                int row = tid >> 3, cseg = (tid & 7) * 64;
                h16* d2 = a.h2 + (((size_t)dir * Tdim + tm1) * Bdim + mtblk * 64 + row) * Hdim + cseg;
                #pragma unroll
                for (int i = 0; i < 8; ++i)
                    *(uint4*)(d2 + i * 8) = *(const uint4*)&sm.H.h[row * 536 + cseg + i * 8];
            }
        };

        for (int t = 0; t < Tdim; ++t) {
            // ---- throttle: upper-X consumed h(t-5) before we overwrite slot ----
            if (l < 2 && t >= 5) {
                for (;;) {
                    int ok = 1;
                    if (tid >= 64 && tid < 72)
                        ok = (ld_flag(&a.zxdone[((u + 1) * 16 + mtblk * 8 + (tid - 64)) * FPAD]) >= t - 4);
                    if (__syncthreads_and(ok)) break;
                    __builtin_amdgcn_s_sleep(1);
                }
                asm volatile("" ::: "memory");
            }
            if (t > 0) {
                convert(t - 1);
                // ---- Wh GEMM: acc = h(t-1) @ Wh (A from LDS, B streamed L2) ----
                #pragma unroll
                for (int mt = 0; mt < 4; ++mt)
                    #pragma unroll
                    for (int n = 0; n < 4; ++n)
                        acc[mt][n] = (float4v){0.f, 0.f, 0.f, 0.f};
                #pragma unroll
                for (int ks = 0; ks < 16; ++ks) {
                    half8 af[4], bf[4];
                    #pragma unroll
                    for (int mt = 0; mt < 4; ++mt)
                        af[mt] = *(const half8*)&sm.H.h[(mt * 16 + r15) * 536 + ks * 32 + quad * 8];
                    #pragma unroll
                    for (int n = 0; n < 4; ++n)
                        bf[n] = *(const half8*)&wbase[n][ks * 1024 + loff];
                    #pragma unroll
                    for (int mt = 0; mt < 4; ++mt)
                        #pragma unroll
                        for (int n = 0; n < 4; ++n)
                            acc[mt][n] = __builtin_amdgcn_mfma_f32_16x16x32_f16(af[mt], bf[n], acc[mt][n], 0, 0, 0);
                }
                __syncthreads();   // drains publish stores; protects h LDS
                if (tid == 0) st_flag_rel(&a.hdone[(u * 2 + mtblk) * FPAD], t);
            } else {
                #pragma unroll
                for (int mt = 0; mt < 4; ++mt)
                    #pragma unroll
                    for (int n = 0; n < 4; ++n)
                        acc[mt][n] = (float4v){0.f, 0.f, 0.f, 0.f};
            }
            // ---- add x-part: zx(t) ----
            if (l > 0) {
                for (;;) {
                    int ok = 1;
                    if (tid < 8) ok = (ld_flag(&a.zxdone[(u * 16 + mtblk * 8 + tid) * FPAD]) >= t + 1);
                    if (__syncthreads_and(ok)) break;
                    __builtin_amdgcn_s_sleep(1);
                }
                asm volatile("" ::: "memory");
                const float* zxb = a.zxbuf + (size_t)(u * 4 + (t & 3)) * 65536;
                #pragma unroll
                for (int mt = 0; mt < 4; ++mt)
                    #pragma unroll
                    for (int n = 0; n < 4; ++n) {
                        int ntg = w4 * 4 + n, gmt = mtblk * 4 + mt;
                        float4v xv = ld16cf(zxb + ((size_t)(ntg * 8 + gmt) * 64 + lane) * 4);
                        acc[mt][n] += xv;
                    }
            } else {
                #pragma unroll
                for (int mt = 0; mt < 4; ++mt)
                    #pragma unroll
                    for (int n = 0; n < 4; ++n) {
                        int ntg = w4 * 4 + n, gmt = mtblk * 4 + mt;
                        const h16* zp = a.zx0f + ((((size_t)dir * Tdim + t) * 32 + ntg) * 8 + gmt) * 256 + lane * 4;
                        union { uint2 uu; h16 hh[4]; } vv;
                        vv.uu = *(const uint2*)zp;
                        #pragma unroll
                        for (int r = 0; r < 4; ++r) acc[mt][n][r] += (float)vv.hh[r];
                    }
            }
        }
        // ---- tail: h(T-1) ----
        if (l < 2) {
            for (;;) {
                int ok = 1;
                if (tid >= 64 && tid < 72)
                    ok = (ld_flag(&a.zxdone[((u + 1) * 16 + mtblk * 8 + (tid - 64)) * FPAD]) >= Tdim - 4);
                if (__syncthreads_and(ok)) break;
                __builtin_amdgcn_s_sleep(1);
            }
            asm volatile("" ::: "memory");
        }
        convert(Tdim - 1);
        __syncthreads();
        if (tid == 0) st_flag_rel(&a.hdone[(u * 2 + mtblk) * FPAD], Tdim);
    } else {
        // ================= X role: pure GEMM h_lower(t) @ Wx + cb =================
        const int xi = blk - 12;
        const int xui = xi >> 4;
        const int xu = (xui < 2) ? (xui + 1) : (xui + 2);   // {1,2,4,5}
        const int sub = xi & 15, mtblk = sub >> 3, cx = sub & 7;
        const int dir = xu / 3, l = xu % 3;
        const int gmt = mtblk * 4 + (w4 & 3);
        const int npair = w4 >> 2;

        #pragma unroll
        for (int i = 0; i < 8; ++i) {
            int f = tid + i * NH;       // 0..4095 frags of Wx slice
            int ks = f >> 8, ntl = (f >> 6) & 3, ln = f & 63;
            int ntg = cx * 4 + ntl;
            const h16* src = a.Wfrag + (((size_t)(xu * 16 + (ntg >> 1)) * 32 + ks) * 2 + (ntg & 1)) * 512 + ln * 8;
            *(uint4*)&sm.X.wx[((size_t)(ks * 4 + ntl) * 64 + ln) * 8] = *(const uint4*)src;
        }
        __syncthreads();

        float cbv[2];
        #pragma unroll
        for (int n = 0; n < 2; ++n) {
            int col = (cx * 4 + npair * 2 + n) * 16 + r15;
            cbv[n] = a.cb[(dir * 3 + l) * Hdim + col];
        }
        const int loflag  = ((xu - 1) * 2 + mtblk) * FPAD;
        const int thrflag = (xu * 2 + mtblk) * FPAD;
        const int myflag  = (xu * 16 + mtblk * 8 + cx) * FPAD;

        for (int t = 0; t < Tdim; ++t) {
            for (;;) {
                int ok = 1;
                if (tid == 0) ok = (ld_flag(&a.hdone[loflag]) >= t + 1);
                else if (tid == 64 && t >= 4) ok = (ld_flag(&a.hdone[thrflag]) >= t - 3);
                if (__syncthreads_and(ok)) break;
                __builtin_amdgcn_s_sleep(1);
            }
            asm volatile("" ::: "memory");

            const h16* hb = a.hbuf + (size_t)((xu - 1) * 4 + (t & 3)) * 65536;
            half8 af[16];
            #pragma unroll
            for (int ks = 0; ks < 16; ++ks)
                af[ks] = ld16c(&hb[((size_t)(ks * 8 + gmt) * 64 + lane) * 8]);
            float4v a0 = {0.f, 0.f, 0.f, 0.f}, a1 = {0.f, 0.f, 0.f, 0.f};
            #pragma unroll
            for (int ks = 0; ks < 16; ++ks) {
                half8 b0 = *(const half8*)&sm.X.wx[((size_t)(ks * 4 + npair * 2 + 0) * 64 + lane) * 8];
                half8 b1 = *(const half8*)&sm.X.wx[((size_t)(ks * 4 + npair * 2 + 1) * 64 + lane) * 8];
                a0 = __builtin_amdgcn_mfma_f32_16x16x32_f16(af[ks], b0, a0, 0, 0, 0);
                a1 = __builtin_amdgcn_mfma_f32_16x16x32_f16(af[ks], b1, a1, 0, 0, 0);
            }
            #pragma unroll
            for (int r = 0; r < 4; ++r) { a0[r] += cbv[0]; a1[r] += cbv[1]; }
            float* zxb = a.zxbuf + (size_t)(xu * 4 + (t & 3)) * 65536;
            int n0 = cx * 4 + npair * 2;
            st16cf(zxb + ((size_t)((n0 + 0) * 8 + gmt) * 64 + lane) * 4, a0);
            st16cf(zxb + ((size_t)((n0 + 1) * 8 + gmt) * 64 + lane) * 4, a1);
            __syncthreads();
            if (tid == 0) st_flag_rel(&a.zxdone[myflag], t + 1);
        }
    }
}

// ---------------- FC: logits = [h_l2r ; gather(h_r2l)] @ W_fc + b_fc -------------
__global__ __launch_bounds__(NTHR) void fc_kernel(
    const h16* __restrict__ h2, const int* __restrict__ pad,
    const float* __restrict__ Wfc, const float* __restrict__ bfc,
    float* __restrict__ out)
{
    __shared__ float sA[64 * 68];
    __shared__ float sB[64 * 48];
    const int blk = blockIdx.x, tid = threadIdx.x;
    const int b = blk >> 2;
    const int j0 = (blk & 3) * 64;
    const int p = pad[b];
    const int rg = tid >> 4;
    const int c0 = (tid & 15) * 3;
    float acc[4][3] = {};

    for (int k0 = 0; k0 < 2 * Hdim; k0 += 64) {
        {
            int rr = tid >> 2;
            int kp = (tid & 3) * 16;
            int j = j0 + rr;
            const h16* src;
            if (k0 < Hdim) {
                src = h2 + (((size_t)0 * Tdim + j) * Bdim + b) * Hdim + k0 + kp;
            } else {
                int idx = (j < p) ? (p - j - 1) : j;
                src = h2 + (((size_t)1 * Tdim + idx) * Bdim + b) * Hdim + (k0 - Hdim) + kp;
            }
            union { uint4 u4; h16 h[8]; } w0, w1;
            w0.u4 = *(const uint4*)src;
            w1.u4 = *(const uint4*)(src + 8);
            #pragma unroll
            for (int i = 0; i < 8; ++i) {
                sA[rr * 68 + kp + i]     = (float)w0.h[i];
                sA[rr * 68 + kp + 8 + i] = (float)w1.h[i];
            }
        }
        for (int e = tid; e < 64 * 48; e += NTHR) {
            int kk = e / 48, c = e - kk * 48;
            sB[e] = (c < NC) ? Wfc[(k0 + kk) * NC + c] : 0.f;
        }
        __syncthreads();
        for (int kk = 0; kk < 64; ++kk) {
            float b0 = sB[kk * 48 + c0 + 0];
            float b1 = sB[kk * 48 + c0 + 1];
            float b2 = sB[kk * 48 + c0 + 2];
            #pragma unroll
            for (int i = 0; i < 4; ++i) {
                float av = sA[(rg * 4 + i) * 68 + kk];
                acc[i][0] += av * b0; acc[i][1] += av * b1; acc[i][2] += av * b2;
            }
        }
        __syncthreads();
    }
    #pragma unroll
    for (int i = 0; i < 4; ++i) {
        int r = blk * 64 + rg * 4 + i;
        #pragma unroll
        for (int jj = 0; jj < 3; ++jj) {
            int c = c0 + jj;
            if (c < NC) out[r * NC + c] = acc[i][jj] + bfc[c];
        }
    }
}

extern "C" void kernel_launch(void* const* d_in, const int* in_sizes, int n_in,
                              void* d_out, int out_size, void* d_ws, size_t ws_size,
                              hipStream_t stream) {
    const float* x      = (const float*)d_in[0];
    const float* rx     = (const float*)d_in[1];
    const int*   pad    = (const int*)d_in[2];
    const float* Wemb   = (const float*)d_in[4];
    const float* bemb   = (const float*)d_in[5];
    const float* Wx_l2r = (const float*)d_in[6];
    const float* bx_l2r = (const float*)d_in[7];
    const float* Wh_l2r = (const float*)d_in[8];
    const float* bh_l2r = (const float*)d_in[9];
    const float* Wx_r2l = (const float*)d_in[10];
    const float* bx_r2l = (const float*)d_in[11];
    const float* Wh_r2l = (const float*)d_in[12];
    const float* bh_r2l = (const float*)d_in[13];
    const float* lng    = (const float*)d_in[14];
    const float* lnb    = (const float*)d_in[15];
    const float* Wfc    = (const float*)d_in[16];
    const float* bfc    = (const float*)d_in[17];

    char* base = (char*)d_ws;
    size_t off = 0;
    auto alloc = [&](size_t bytes) { char* p = base + off; off += (bytes + 255) & ~(size_t)255; return p; };
    h16*   zx0f  = (h16*)  alloc((size_t)2 * Tdim * 32 * 8 * 64 * 4 * 2);      // 67 MB
    h16*   h2    = (h16*)  alloc((size_t)2 * Tdim * Bdim * Hdim * 2);          // 67 MB
    h16*   Wfrag = (h16*)  alloc((size_t)6 * 16 * 32768 * 2);                  // 6.3 MB
    h16*   W0f   = (h16*)  alloc((size_t)2 * 32 * 10 * 64 * 8 * 2);            // 0.66 MB
    h16*   hbuf  = (h16*)  alloc((size_t)6 * 4 * 65536 * 2);                   // 3.1 MB
    float* zxbuf = (float*)alloc((size_t)6 * 4 * 65536 * 4);                   // 6.3 MB
    float* W0    = (float*)alloc((size_t)2 * KXdim * Hdim * 4);
    float* cb    = (float*)alloc((size_t)2 * 3 * Hdim * 4);
    int*   hdone  = (int*) alloc((size_t)12 * FPAD * 4);
    int*   zxdone = (int*) alloc((size_t)96 * FPAD * 4);

    prep1_kernel<<<(2 * KXdim * Hdim + 2 * 3 * Hdim) / NTHR, NTHR, 0, stream>>>(
        Wemb, bemb, Wx_l2r, bx_l2r, bh_l2r, Wx_r2l, bx_r2l, bh_r2l, W0, cb);

    pack_W_kernel<<<(6 * 16 * 32 * 2 * 64 * 8) / NTHR, NTHR, 0, stream>>>(
        W0, Wx_l2r, Wh_l2r, Wx_r2l, Wh_r2l, Wfrag);

    pack_W0f_kernel<<<(2 * 32 * 10 * 64 * 8) / NTHR, NTHR, 0, stream>>>(W0, W0f);

    zx0_kernel<<<1024, NTHR, 0, stream>>>(x, rx, W0f, cb, zx0f);

    zeroinit_kernel<<<(96 * FPAD + NTHR - 1) / NTHR, NTHR, 0, stream>>>(hdone, zxdone);

    PipeArgs a;
    a.Wfrag = Wfrag; a.zx0f = zx0f; a.cb = cb; a.lng = lng; a.lnb = lnb;
    a.hbuf = hbuf; a.zxbuf = zxbuf; a.h2 = h2;
    a.hdone = hdone; a.zxdone = zxdone;
    void* kargs[] = { &a };
    hipLaunchCooperativeKernel((void*)rnn_pipe, dim3(76), dim3(NH), kargs, 0, stream);

    fc_kernel<<<(Bdim * Tdim) / 64, NTHR, 0, stream>>>(h2, pad, Wfc, bfc, (float*)d_out);
}